// Round 6
// baseline (96.084 us; speedup 1.0000x reference)
//
#include <hip/hip_runtime.h>
#include <math.h>

#define BB 256
#define DD 128
#define CC 8000
#define EPSF 1e-12f
#define SCALEF 64.0f
#define MARGINF 0.5f

// ---------------------------------------------------------------------------
// Kernel A: fused prep + dual GEMM + epilogue. Grid 32(c) x 32(r) = 1024
// blocks x 256 thr -> 4 blocks/CU, 16 waves/CU, 4 waves/SIMD (2x R5's
// concurrency for w-load latency hiding). Tile 8 rows x 256 cols.
//   phase 1: local prep into LDS — normalize 8 embds rows (neS), gather+
//            normalize 8 label columns of w (gS), s1 per row.
//   phase 2: dual GEMM over d streaming w (float4, L2-resident). Column
//            norms accumulated FOR FREE from the same streamed w values.
//   phase 3: epilogue — penalties final; e = exp(64*cos) UNNORMALIZED into
//            logits region (arg<=64 fits fp32); per-(row,cblock) partial
//            sums to psums (no atomics).
// ---------------------------------------------------------------------------
__global__ __launch_bounds__(256, 4) void fused_kernel(
    const float* __restrict__ embds, const float* __restrict__ w,
    const int* __restrict__ labels, float* __restrict__ out,
    float* __restrict__ psums) {
  __shared__ float neS[DD * 8];
  __shared__ float gS[DD * 8];
  __shared__ float s1S[8];
  __shared__ int labS[8];

  int tid = threadIdx.x;
  int c0 = blockIdx.x * 256;
  int r0 = blockIdx.y * 8;

  // ---- phase 1: local prep (8 rows x 32 threads each, 4 d's per thread) ----
  {
    int r = tid >> 5;           // 0..7 local row (each 32-lane group = 1 row)
    int k = tid & 31;           // 0..31, each handles 4 d's
    int row = r0 + r;
    int lab = labels[row];
    float4 ea = *(const float4*)(embds + row * DD + k * 4);
    float ev[4] = {ea.x, ea.y, ea.z, ea.w};
    float wl[4];
    float se = 0.f, sw = 0.f, sx = 0.f;
    #pragma unroll
    for (int i = 0; i < 4; ++i) {
      wl[i] = w[(k * 4 + i) * CC + lab];
      se = fmaf(ev[i], ev[i], se);
      sw = fmaf(wl[i], wl[i], sw);
      sx = fmaf(ev[i], wl[i], sx);
    }
    // reduce within the 32-lane row group (xor 1..16 stays in-group)
    #pragma unroll
    for (int off = 1; off < 32; off <<= 1) {
      se += __shfl_xor(se, off, 64);
      sw += __shfl_xor(sw, off, 64);
      sx += __shfl_xor(sx, off, 64);
    }
    float rn = rsqrtf(fmaxf(se, EPSF));
    float rl = rsqrtf(fmaxf(sw, EPSF));
    #pragma unroll
    for (int i = 0; i < 4; ++i) {
      neS[(k * 4 + i) * 8 + r] = ev[i] * rn;
      gS[(k * 4 + i) * 8 + r] = wl[i] * rl;
    }
    if (k == 0) { s1S[r] = sx * rn * rl; labS[r] = lab; }
  }
  __syncthreads();

  // ---- phase 2: dual GEMM, w streamed once per block ----
  int tx = tid & 63;
  int ty = tid >> 6;            // wave id -> row pair (wave-uniform)
  int c = c0 + tx * 4;
  bool cok = c < CC;
  const float4* w4 = (const float4*)w;
  int wbase = (c0 >> 2) + tx;

  float accC[2][4], accG[2][4], colsum[4];
  #pragma unroll
  for (int rr = 0; rr < 2; ++rr)
    #pragma unroll
    for (int j = 0; j < 4; ++j) { accC[rr][j] = 0.f; accG[rr][j] = 0.f; }
  #pragma unroll
  for (int j = 0; j < 4; ++j) colsum[j] = 0.f;

  #pragma unroll 8
  for (int d = 0; d < DD; ++d) {
    float4 wv = cok ? w4[d * (CC / 4) + wbase] : make_float4(0.f, 0.f, 0.f, 0.f);
    float2 a = *(const float2*)&neS[d * 8 + ty * 2];  // wave-uniform broadcast
    float2 g = *(const float2*)&gS[d * 8 + ty * 2];
    float av[2] = {a.x, a.y};
    float gv[2] = {g.x, g.y};
    float wj[4] = {wv.x, wv.y, wv.z, wv.w};
    #pragma unroll
    for (int j = 0; j < 4; ++j) colsum[j] = fmaf(wj[j], wj[j], colsum[j]);
    #pragma unroll
    for (int rr = 0; rr < 2; ++rr) {
      #pragma unroll
      for (int j = 0; j < 4; ++j) {
        accC[rr][j] = fmaf(av[rr], wj[j], accC[rr][j]);
        accG[rr][j] = fmaf(gv[rr], wj[j], accG[rr][j]);
      }
    }
  }

  // ---- phase 3: epilogue ----
  float rcj[4];
  #pragma unroll
  for (int j = 0; j < 4; ++j) rcj[j] = rsqrtf(fmaxf(colsum[j], EPSF));

  float* pen_base = out + (size_t)BB * CC;
  #pragma unroll
  for (int rr = 0; rr < 2; ++rr) {
    int lr = ty * 2 + rr;
    int row = r0 + lr;
    float s1v = s1S[lr];
    int lab = labS[lr];
    float penv[4], eo[4];
    float psum = 0.f;
    #pragma unroll
    for (int j = 0; j < 4; ++j) {
      float cs = accC[rr][j] * rcj[j];
      float gw = accG[rr][j] * rcj[j];
      float win = (s1v - cs) * rsqrtf(fmaxf(2.f - 2.f * gw, EPSF));
      if (c + j == lab) win = 0.f;
      penv[j] = MARGINF - fminf(MARGINF, win);
      float e = cok ? __expf(SCALEF * cs) : 0.f;
      eo[j] = e;
      psum += e;
    }
    if (cok) {
      size_t o4 = (size_t)row * (CC / 4) + wbase;
      ((float4*)pen_base)[o4] = make_float4(penv[0], penv[1], penv[2], penv[3]);
      ((float4*)out)[o4] = make_float4(eo[0], eo[1], eo[2], eo[3]);
    }
    // wave reduction of psum (all 64 lanes hold this row)
    #pragma unroll
    for (int off = 1; off < 64; off <<= 1) psum += __shfl_xor(psum, off, 64);
    if (tx == 0) psums[row * 32 + blockIdx.x] = psum;
  }
}

// ---------------------------------------------------------------------------
// Kernel B: per-row normalize. 512 blocks x 256 thr (2/CU). Each block:
// half a row — sum the 32 partials, scale 1000 float4s in place (L2-warm).
// ---------------------------------------------------------------------------
__global__ __launch_bounds__(256) void scale_kernel(
    float* __restrict__ out, const float* __restrict__ psums) {
  __shared__ float invS;
  int r = blockIdx.x >> 1;
  int half = blockIdx.x & 1;
  int tid = threadIdx.x;
  if (tid < 64) {
    float p = (tid < 32) ? psums[r * 32 + tid] : 0.f;
    #pragma unroll
    for (int off = 1; off < 32; off <<= 1) p += __shfl_xor(p, off, 64);
    if (tid == 0) invS = 1.f / p;
  }
  __syncthreads();
  float inv = invS;
  float4* seg = (float4*)out + (size_t)r * (CC / 4) + half * 1000;
  #pragma unroll
  for (int k = 0; k < 4; ++k) {
    int i = tid + k * 256;
    if (i < 1000) {
      float4 v = seg[i];
      seg[i] = make_float4(v.x * inv, v.y * inv, v.z * inv, v.w * inv);
    }
  }
}

extern "C" void kernel_launch(void* const* d_in, const int* in_sizes, int n_in,
                              void* d_out, int out_size, void* d_ws, size_t ws_size,
                              hipStream_t stream) {
  const float* embds = (const float*)d_in[0];
  const float* w = (const float*)d_in[1];
  const int* labels = (const int*)d_in[2];
  float* out = (float*)d_out;
  float* psums = (float*)d_ws;    // [256][32]

  dim3 gA(32, 32);
  fused_kernel<<<gA, 256, 0, stream>>>(embds, w, labels, out, psums);
  scale_kernel<<<512, 256, 0, stream>>>(out, psums);
}